// Round 1
// baseline (3043.461 us; speedup 1.0000x reference)
//
#include <hip/hip_runtime.h>
#include <hip/hip_fp16.h>
#include <math.h>

// ---------------------------------------------------------------------------
// RNN: h_{t+1} = relu(x_t @ W_in^T + h_t @ W_hh^T + b_hh + noise_t*scale)
// outputs: hidden_list [128,256,1024] f32, output_list [128,256,128] f32,
//          h_final [128,1024] f32   (concatenated flat in d_out)
//
// Design:
//  - fp16 MFMA (f32 accum) for all GEMMs; threshold 0.159 gives ~8x margin.
//  - Concatenate K: [h | x_t] @ [W_hh | W_in]^T, K=1152.
//  - 128 persistent blocks = 8 batch-groups (16 rows) x 16 col-slices (64 cols).
//    W slice (64 x 1152 fp16, padded) lives in LDS for the whole kernel.
//  - Per-step barrier only among the 16 blocks of a batch-group (atomic
//    counter per (group, step), agent scope). h exchanged via coherent
//    (agent-scope relaxed atomic) loads/stores => correct across XCDs.
//  - Readout GEMM (y = h @ W_out^T) done afterwards as one parallel kernel.
// ---------------------------------------------------------------------------

typedef _Float16 half8 __attribute__((ext_vector_type(8)));
typedef float    f32x4 __attribute__((ext_vector_type(4)));
typedef unsigned short ushort8 __attribute__((ext_vector_type(8)));

#define SIGMA_F 0.05f

constexpr int T_  = 256;
constexpr int B_  = 128;
constexpr int NH  = 1024;
constexpr int NIN = 128;
constexpr int KC  = NH + NIN;       // 1152 concatenated K
constexpr int GM  = 8;              // batch groups
constexpr int GN  = 16;             // column slices
constexpr int MB  = 16;             // batch rows per group
constexpr int NSUB = 64;            // hidden cols per block
constexpr int WROW = KC + 8;        // padded LDS row (halves); keeps 16B align

// workspace layout (bytes)
constexpr size_t OFF_XH  = 0;                          // u16 [B_*T_*NIN]   8.39 MB
constexpr size_t OFF_NB  = (size_t)B_*T_*NIN*2;        // f32 [T_*NH]       1.05 MB
constexpr size_t OFF_WO  = OFF_NB + (size_t)T_*NH*4;   // u16 [NIN*NH]      0.26 MB
constexpr size_t OFF_HB  = OFF_WO + (size_t)NIN*NH*2;  // u32 [2][B_*NH/2]  0.52 MB
constexpr size_t OFF_CNT = OFF_HB + (size_t)2*B_*NH/2*4; // u32 [GM*T_]     8 KB

__device__ __forceinline__ unsigned short f16bits(float v) {
    return __half_as_ushort(__float2half(v));
}

// ---------------------------------------------------------------------------
__global__ void setup_kernel(const float* __restrict__ X,
                             const float* __restrict__ hidden,
                             const float* __restrict__ b_hh,
                             const float* __restrict__ W_out,
                             const float* __restrict__ alpha_w,
                             const float* __restrict__ noise,
                             unsigned short* __restrict__ Xh,
                             float* __restrict__ NB,
                             unsigned short* __restrict__ Wo,
                             unsigned int* __restrict__ Hb0,
                             unsigned int* __restrict__ cnt)
{
    int idx = blockIdx.x * 256 + threadIdx.x;
    if (idx < B_ * T_ * NIN) {
        Xh[idx] = f16bits(X[idx]);
    }
    if (idx < T_ * NH) {
        int c = idx & (NH - 1);
        NB[idx] = b_hh[c] + noise[idx] * (sqrtf(2.0f / alpha_w[c]) * SIGMA_F);
    }
    if (idx < NIN * NH) {
        Wo[idx] = f16bits(W_out[idx]);
    }
    if (idx < B_ * NH / 2) {
        unsigned int lo = f16bits(hidden[idx * 2]);
        unsigned int hi = f16bits(hidden[idx * 2 + 1]);
        Hb0[idx] = lo | (hi << 16);
    }
    if (idx < GM * T_) cnt[idx] = 0u;
}

// ---------------------------------------------------------------------------
// Persistent recurrent kernel: 128 blocks x 256 threads, 1 block/CU (LDS-bound)
__global__ __launch_bounds__(256, 1) void rnn_step_kernel(
    const float* __restrict__ W_hh, const float* __restrict__ W_in,
    const unsigned short* __restrict__ Xh, const float* __restrict__ NB,
    unsigned int* __restrict__ Hb0, unsigned int* __restrict__ Hb1,
    unsigned int* __restrict__ cnt,
    float* __restrict__ hidden_list, float* __restrict__ h_final)
{
    __shared__ _Float16 wlds[NSUB * WROW];   // 64 x 1160 fp16 = 148,480 B

    const int tid = threadIdx.x;
    const int m = blockIdx.x / GN;   // batch group
    const int n = blockIdx.x % GN;   // column slice

    // Load this block's W slice: rows = global hidden cols, K = [W_hh | W_in]
    for (int idx = tid; idx < NSUB * KC; idx += 256) {
        int nl = idx / KC, k = idx - nl * KC;
        int gc = n * NSUB + nl;
        float v = (k < NH) ? W_hh[gc * NH + k] : W_in[gc * NIN + (k - NH)];
        wlds[nl * WROW + k] = (_Float16)v;
    }
    __syncthreads();

    const int wave = tid >> 6, lane = tid & 63;
    const int l15 = lane & 15, lk = lane >> 4;
    const int rowA = m * MB + l15;          // batch row this lane loads (A frag)
    const int colW = wave * 16 + l15;       // local W row (this wave's n-tile)
    const int gcol = n * NSUB + colW;       // global hidden col (D col)
    const int wbase = colW * WROW;

    for (int t = 0; t < T_; ++t) {
        unsigned int* hcur  = (t & 1) ? Hb1 : Hb0;
        unsigned int* hnext = (t & 1) ? Hb0 : Hb1;

        f32x4 acc = {0.f, 0.f, 0.f, 0.f};

        // ---- x_t contribution (K part 1024..1151), normal cached loads ----
        {
            const ushort8* xp = (const ushort8*)(Xh + (rowA * T_ + t) * NIN + lk * 8);
            #pragma unroll
            for (int ki = 0; ki < 4; ++ki) {
                ushort8 araw = xp[ki * 4];          // +32 halves per k-iter
                half8 a = __builtin_bit_cast(half8, araw);
                half8 b = *(const half8*)&wlds[wbase + NH + ki * 32 + lk * 8];
                acc = __builtin_amdgcn_mfma_f32_16x16x32_f16(a, b, acc, 0, 0, 0);
            }
        }
        // ---- h contribution (K part 0..1023), coherent (agent) loads ----
        {
            const unsigned long long* hp =
                (const unsigned long long*)hcur + (size_t)rowA * 256 + lk * 2;
            #pragma unroll
            for (int ki = 0; ki < 32; ++ki) {
                union { unsigned long long q[2]; half8 h; } u;
                u.q[0] = __hip_atomic_load(hp + (size_t)ki * 8,
                                           __ATOMIC_RELAXED, __HIP_MEMORY_SCOPE_AGENT);
                u.q[1] = __hip_atomic_load(hp + (size_t)ki * 8 + 1,
                                           __ATOMIC_RELAXED, __HIP_MEMORY_SCOPE_AGENT);
                half8 b = *(const half8*)&wlds[wbase + ki * 32 + lk * 8];
                acc = __builtin_amdgcn_mfma_f32_16x16x32_f16(u.h, b, acc, 0, 0, 0);
            }
        }

        // ---- epilogue: bias+noise, relu, write fp32 outputs ----
        const float nb = NB[t * NH + gcol];
        float hv[4];
        #pragma unroll
        for (int r = 0; r < 4; ++r) {
            float v = acc[r] + nb;
            v = v > 0.f ? v : 0.f;
            hv[r] = v;
            int brow = m * MB + lk * 4 + r;
            hidden_list[((size_t)brow * T_ + t) * NH + gcol] = v;
            if (t == T_ - 1) h_final[(size_t)brow * NH + gcol] = v;
        }
        // pack fp16 pairs (even lane holds cols {gcol, gcol+1}) and store
        // coherently for next step's cross-block reads
        #pragma unroll
        for (int r = 0; r < 4; ++r) {
            float other = __shfl_xor(hv[r], 1);
            if (!(lane & 1)) {
                unsigned int val = (unsigned int)f16bits(hv[r]) |
                                   ((unsigned int)f16bits(other) << 16);
                int brow = m * MB + lk * 4 + r;
                __hip_atomic_store(&hnext[(size_t)brow * 512 + (gcol >> 1)], val,
                                   __ATOMIC_RELAXED, __HIP_MEMORY_SCOPE_AGENT);
            }
        }

        // ---- per-domain barrier (16 blocks sharing batch group m) ----
        if (t < T_ - 1) {
            asm volatile("s_waitcnt vmcnt(0)" ::: "memory"); // drain own stores
            __syncthreads();
            if (tid == 0) {
                __hip_atomic_fetch_add(&cnt[m * T_ + t], 1u,
                                       __ATOMIC_RELEASE, __HIP_MEMORY_SCOPE_AGENT);
                unsigned int v;
                do {
                    __builtin_amdgcn_s_sleep(4);
                    v = __hip_atomic_load(&cnt[m * T_ + t],
                                          __ATOMIC_ACQUIRE, __HIP_MEMORY_SCOPE_AGENT);
                } while (v < (unsigned int)GN);
            }
            __syncthreads();
        }
    }
}

// ---------------------------------------------------------------------------
// Readout: Y[32768,128] = HL[32768,1024](f32->f16) @ Wo^T(f16), fp32 out.
// 512 blocks x 256 thr; block tile 64Mx128N; wave: 4 m-tiles x 2 n-tiles.
__global__ __launch_bounds__(256, 4) void ygemm_kernel(
    const float* __restrict__ HL, const unsigned short* __restrict__ Wo,
    float* __restrict__ Y)
{
    const int tid = threadIdx.x;
    const int wave = tid >> 6, lane = tid & 63;
    const int l15 = lane & 15, lk = lane >> 4;
    const size_t rowbase = (size_t)blockIdx.x * 64;

    f32x4 acc[4][2] = {};

    #pragma unroll 2
    for (int ki = 0; ki < 32; ++ki) {
        const int k0 = ki * 32 + lk * 8;
        half8 bfr[2];
        #pragma unroll
        for (int nt = 0; nt < 2; ++nt) {
            int ncol = (wave * 2 + nt) * 16 + l15;
            ushort8 braw = *(const ushort8*)(Wo + ncol * NH + k0);
            bfr[nt] = __builtin_bit_cast(half8, braw);
        }
        #pragma unroll
        for (int mt = 0; mt < 4; ++mt) {
            size_t row = rowbase + mt * 16 + l15;
            const float4* ap = (const float4*)(HL + row * NH + k0);
            float4 a0 = ap[0];
            float4 a1 = ap[1];
            half8 a = { (_Float16)a0.x, (_Float16)a0.y, (_Float16)a0.z, (_Float16)a0.w,
                        (_Float16)a1.x, (_Float16)a1.y, (_Float16)a1.z, (_Float16)a1.w };
            #pragma unroll
            for (int nt = 0; nt < 2; ++nt)
                acc[mt][nt] = __builtin_amdgcn_mfma_f32_16x16x32_f16(a, bfr[nt], acc[mt][nt], 0, 0, 0);
        }
    }

    #pragma unroll
    for (int mt = 0; mt < 4; ++mt) {
        #pragma unroll
        for (int nt = 0; nt < 2; ++nt) {
            int ncol = (wave * 2 + nt) * 16 + l15;
            #pragma unroll
            for (int r = 0; r < 4; ++r) {
                size_t row = rowbase + mt * 16 + lk * 4 + r;
                Y[row * NIN + ncol] = acc[mt][nt][r];
            }
        }
    }
}

// ---------------------------------------------------------------------------
extern "C" void kernel_launch(void* const* d_in, const int* in_sizes, int n_in,
                              void* d_out, int out_size, void* d_ws, size_t ws_size,
                              hipStream_t stream)
{
    const float* X      = (const float*)d_in[0];  // [128,256,128]
    const float* hidden = (const float*)d_in[1];  // [128,1024]
    const float* W_in   = (const float*)d_in[2];  // [1024,128]
    const float* W_hh   = (const float*)d_in[3];  // [1024,1024]
    const float* b_hh   = (const float*)d_in[4];  // [1024]
    const float* W_out  = (const float*)d_in[5];  // [128,1024]
    const float* alpha  = (const float*)d_in[6];  // [1024]
    const float* noise  = (const float*)d_in[7];  // [256,1024]

    char* ws = (char*)d_ws;   // needs ~10.2 MB
    unsigned short* Xh = (unsigned short*)(ws + OFF_XH);
    float*          NB = (float*)(ws + OFF_NB);
    unsigned short* Wo = (unsigned short*)(ws + OFF_WO);
    unsigned int*  Hb0 = (unsigned int*)(ws + OFF_HB);
    unsigned int*  Hb1 = Hb0 + (size_t)B_ * NH / 2;
    unsigned int*  cnt = (unsigned int*)(ws + OFF_CNT);

    float* hidden_list = (float*)d_out;                                  // [128,256,1024]
    float* output_list = hidden_list + (size_t)B_ * T_ * NH;             // [128,256,128]
    float* h_final     = output_list + (size_t)B_ * T_ * NIN;            // [128,1024]

    setup_kernel<<<(B_ * T_ * NIN + 255) / 256, 256, 0, stream>>>(
        X, hidden, b_hh, W_out, alpha, noise, Xh, NB, Wo, Hb0, cnt);

    rnn_step_kernel<<<GM * GN, 256, 0, stream>>>(
        W_hh, W_in, Xh, NB, Hb0, Hb1, cnt, hidden_list, h_final);

    ygemm_kernel<<<(B_ * T_) / 64, 256, 0, stream>>>(
        hidden_list, Wo, output_list);
}

// Round 2
// 2376.278 us; speedup vs baseline: 1.2808x; 1.2808x over previous
//
#include <hip/hip_runtime.h>
#include <hip/hip_fp16.h>
#include <math.h>

// ---------------------------------------------------------------------------
// RNN: h_{t+1} = relu(x_t @ W_in^T + h_t @ W_hh^T + b_hh + noise_t*scale)
// outputs: hidden_list [128,256,1024] f32, output_list [128,256,128] f32,
//          h_final [128,1024] f32   (concatenated flat in d_out)
//
// Design (R2):
//  - fp16 MFMA (f32 accum); absmax 0.031 vs threshold 0.159 (R1 measured).
//  - Concatenate K: [h | x_t] @ [W_hh | W_in]^T, K=1152.
//  - 128 persistent blocks = 8 batch-groups (16 rows) x 16 col-slices (64 cols).
//    W slice (64 x 1152 fp16, padded) stationary in LDS.
//  - Cross-block h exchange + barrier: agent-scope RELAXED atomics only
//    (coherent at L3, bypass L2) -- NO acquire/release: those emitted
//    buffer_inv/wbl2 per poll and caused R1's 25x HBM over-fetch + 11.7us/step.
//    Ordering: s_waitcnt vmcnt(0) before arrival; control-dep + syncthreads
//    after poll.
//  - hidden_list stores + x-part MFMAs of step t+1 overlapped with poll.
// ---------------------------------------------------------------------------

typedef _Float16 half8 __attribute__((ext_vector_type(8)));
typedef float    f32x4 __attribute__((ext_vector_type(4)));
typedef unsigned short ushort8 __attribute__((ext_vector_type(8)));

#define SIGMA_F 0.05f

constexpr int T_  = 256;
constexpr int B_  = 128;
constexpr int NH  = 1024;
constexpr int NIN = 128;
constexpr int KC  = NH + NIN;       // 1152 concatenated K
constexpr int GM  = 8;              // batch groups
constexpr int GN  = 16;             // column slices
constexpr int MB  = 16;             // batch rows per group
constexpr int NSUB = 64;            // hidden cols per block
constexpr int WROW = KC + 8;        // padded LDS row (halves); keeps 16B align

// workspace layout (bytes)
constexpr size_t OFF_XH  = 0;                          // u16 [B_*T_*NIN]   8.39 MB
constexpr size_t OFF_NB  = (size_t)B_*T_*NIN*2;        // f32 [T_*NH]       1.05 MB
constexpr size_t OFF_WO  = OFF_NB + (size_t)T_*NH*4;   // u16 [NIN*NH]      0.26 MB
constexpr size_t OFF_HB  = OFF_WO + (size_t)NIN*NH*2;  // u32 [2][B_*NH/2]  0.52 MB
constexpr size_t OFF_CNT = OFF_HB + (size_t)2*B_*NH/2*4; // u32 [GM*T_]     8 KB

__device__ __forceinline__ unsigned short f16bits(float v) {
    return __half_as_ushort(__float2half(v));
}

// ---------------------------------------------------------------------------
__global__ void setup_kernel(const float* __restrict__ X,
                             const float* __restrict__ hidden,
                             const float* __restrict__ b_hh,
                             const float* __restrict__ W_out,
                             const float* __restrict__ alpha_w,
                             const float* __restrict__ noise,
                             unsigned short* __restrict__ Xh,
                             float* __restrict__ NB,
                             unsigned short* __restrict__ Wo,
                             unsigned int* __restrict__ Hb0,
                             unsigned int* __restrict__ cnt)
{
    int idx = blockIdx.x * 256 + threadIdx.x;
    if (idx < B_ * T_ * NIN) {
        Xh[idx] = f16bits(X[idx]);
    }
    if (idx < T_ * NH) {
        int c = idx & (NH - 1);
        NB[idx] = b_hh[c] + noise[idx] * (sqrtf(2.0f / alpha_w[c]) * SIGMA_F);
    }
    if (idx < NIN * NH) {
        Wo[idx] = f16bits(W_out[idx]);
    }
    if (idx < B_ * NH / 2) {
        unsigned int lo = f16bits(hidden[idx * 2]);
        unsigned int hi = f16bits(hidden[idx * 2 + 1]);
        Hb0[idx] = lo | (hi << 16);
    }
    if (idx < GM * T_) cnt[idx] = 0u;
}

// ---------------------------------------------------------------------------
// Persistent recurrent kernel: 128 blocks x 256 threads, 1 block/CU (LDS-bound)
__global__ __launch_bounds__(256, 1) void rnn_step_kernel(
    const float* __restrict__ W_hh, const float* __restrict__ W_in,
    const unsigned short* __restrict__ Xh, const float* __restrict__ NB,
    unsigned int* __restrict__ Hb0, unsigned int* __restrict__ Hb1,
    unsigned int* __restrict__ cnt,
    float* __restrict__ hidden_list, float* __restrict__ h_final)
{
    __shared__ _Float16 wlds[NSUB * WROW];   // 64 x 1160 fp16 = 148,480 B

    const int tid = threadIdx.x;
    const int m = blockIdx.x / GN;   // batch group
    const int n = blockIdx.x % GN;   // column slice

    // Load this block's W slice: rows = global hidden cols, K = [W_hh | W_in]
    for (int idx = tid; idx < NSUB * KC; idx += 256) {
        int nl = idx / KC, k = idx - nl * KC;
        int gc = n * NSUB + nl;
        float v = (k < NH) ? W_hh[gc * NH + k] : W_in[gc * NIN + (k - NH)];
        wlds[nl * WROW + k] = (_Float16)v;
    }
    __syncthreads();

    const int wave = tid >> 6, lane = tid & 63;
    const int l15 = lane & 15, lk = lane >> 4;
    const int rowA = m * MB + l15;          // batch row this lane loads (A frag)
    const int colW = wave * 16 + l15;       // local W row (this wave's n-tile)
    const int gcol = n * NSUB + colW;       // global hidden col (D col)
    const int wbase = colW * WROW;

    // x-part of step t accumulated into acc (4 MFMAs, cached loads)
    auto xpart = [&](int t) -> f32x4 {
        f32x4 a = {0.f, 0.f, 0.f, 0.f};
        const ushort8* xp = (const ushort8*)(Xh + (rowA * T_ + t) * NIN + lk * 8);
        #pragma unroll
        for (int ki = 0; ki < 4; ++ki) {
            ushort8 araw = xp[ki * 4];
            half8 av = __builtin_bit_cast(half8, araw);
            half8 bv = *(const half8*)&wlds[wbase + NH + ki * 32 + lk * 8];
            a = __builtin_amdgcn_mfma_f32_16x16x32_f16(av, bv, a, 0, 0, 0);
        }
        return a;
    };

    f32x4 accx = xpart(0);

    for (int t = 0; t < T_; ++t) {
        unsigned int* hcur  = (t & 1) ? Hb1 : Hb0;
        unsigned int* hnext = (t & 1) ? Hb0 : Hb1;

        const float nb = NB[t * NH + gcol];
        f32x4 acc = accx;

        // ---- h contribution (K 0..1023), L3-coherent relaxed loads ----
        {
            const unsigned long long* hp =
                (const unsigned long long*)hcur + (size_t)rowA * 256 + lk * 2;
            #pragma unroll
            for (int ki = 0; ki < 32; ++ki) {
                union { unsigned long long q[2]; half8 h; } u;
                u.q[0] = __hip_atomic_load(hp + (size_t)ki * 8,
                                           __ATOMIC_RELAXED, __HIP_MEMORY_SCOPE_AGENT);
                u.q[1] = __hip_atomic_load(hp + (size_t)ki * 8 + 1,
                                           __ATOMIC_RELAXED, __HIP_MEMORY_SCOPE_AGENT);
                half8 bv = *(const half8*)&wlds[wbase + ki * 32 + lk * 8];
                acc = __builtin_amdgcn_mfma_f32_16x16x32_f16(u.h, bv, acc, 0, 0, 0);
            }
        }

        // ---- bias+noise, relu ----
        float hv[4];
        #pragma unroll
        for (int r = 0; r < 4; ++r) {
            float v = acc[r] + nb;
            hv[r] = v > 0.f ? v : 0.f;
        }

        // ---- pack fp16 pairs, coherent store for next step's readers ----
        #pragma unroll
        for (int r = 0; r < 4; ++r) {
            float other = __shfl_xor(hv[r], 1);
            if (!(lane & 1)) {
                unsigned int val = (unsigned int)f16bits(hv[r]) |
                                   ((unsigned int)f16bits(other) << 16);
                int brow = m * MB + lk * 4 + r;
                __hip_atomic_store(&hnext[(size_t)brow * 512 + (gcol >> 1)], val,
                                   __ATOMIC_RELAXED, __HIP_MEMORY_SCOPE_AGENT);
            }
        }

        asm volatile("s_waitcnt vmcnt(0)" ::: "memory"); // hnext visible at L3
        __syncthreads();                                  // whole block arrived

        if (t < T_ - 1) {
            // arrive first ...
            if (tid == 0) {
                __hip_atomic_fetch_add(&cnt[m * T_ + t], 1u,
                                       __ATOMIC_RELAXED, __HIP_MEMORY_SCOPE_AGENT);
            }
            // ... then overlap fp32 output stores + next x-part with the wait
            #pragma unroll
            for (int r = 0; r < 4; ++r) {
                int brow = m * MB + lk * 4 + r;
                hidden_list[((size_t)brow * T_ + t) * NH + gcol] = hv[r];
            }
            accx = xpart(t + 1);

            if (tid == 0) {
                unsigned int v = __hip_atomic_load(&cnt[m * T_ + t],
                                                   __ATOMIC_RELAXED, __HIP_MEMORY_SCOPE_AGENT);
                while (v < (unsigned int)GN) {
                    __builtin_amdgcn_s_sleep(2);
                    v = __hip_atomic_load(&cnt[m * T_ + t],
                                          __ATOMIC_RELAXED, __HIP_MEMORY_SCOPE_AGENT);
                }
            }
            __syncthreads();
        } else {
            #pragma unroll
            for (int r = 0; r < 4; ++r) {
                int brow = m * MB + lk * 4 + r;
                hidden_list[((size_t)brow * T_ + t) * NH + gcol] = hv[r];
                h_final[(size_t)brow * NH + gcol] = hv[r];
            }
        }
    }
}

// ---------------------------------------------------------------------------
// Readout: Y[32768,128] = HL[32768,1024](f32->f16) @ Wo^T(f16), fp32 out.
// 512 blocks x 256 thr; block tile 64Mx128N; wave: 4 m-tiles x 2 n-tiles.
__global__ __launch_bounds__(256, 4) void ygemm_kernel(
    const float* __restrict__ HL, const unsigned short* __restrict__ Wo,
    float* __restrict__ Y)
{
    const int tid = threadIdx.x;
    const int wave = tid >> 6, lane = tid & 63;
    const int l15 = lane & 15, lk = lane >> 4;
    const size_t rowbase = (size_t)blockIdx.x * 64;

    f32x4 acc[4][2] = {};

    #pragma unroll 2
    for (int ki = 0; ki < 32; ++ki) {
        const int k0 = ki * 32 + lk * 8;
        half8 bfr[2];
        #pragma unroll
        for (int nt = 0; nt < 2; ++nt) {
            int ncol = (wave * 2 + nt) * 16 + l15;
            ushort8 braw = *(const ushort8*)(Wo + ncol * NH + k0);
            bfr[nt] = __builtin_bit_cast(half8, braw);
        }
        #pragma unroll
        for (int mt = 0; mt < 4; ++mt) {
            size_t row = rowbase + mt * 16 + l15;
            const float4* ap = (const float4*)(HL + row * NH + k0);
            float4 a0 = ap[0];
            float4 a1 = ap[1];
            half8 a = { (_Float16)a0.x, (_Float16)a0.y, (_Float16)a0.z, (_Float16)a0.w,
                        (_Float16)a1.x, (_Float16)a1.y, (_Float16)a1.z, (_Float16)a1.w };
            #pragma unroll
            for (int nt = 0; nt < 2; ++nt)
                acc[mt][nt] = __builtin_amdgcn_mfma_f32_16x16x32_f16(a, bfr[nt], acc[mt][nt], 0, 0, 0);
        }
    }

    #pragma unroll
    for (int mt = 0; mt < 4; ++mt) {
        #pragma unroll
        for (int nt = 0; nt < 2; ++nt) {
            int ncol = (wave * 2 + nt) * 16 + l15;
            #pragma unroll
            for (int r = 0; r < 4; ++r) {
                size_t row = rowbase + mt * 16 + lk * 4 + r;
                Y[row * NIN + ncol] = acc[mt][nt][r];
            }
        }
    }
}

// ---------------------------------------------------------------------------
extern "C" void kernel_launch(void* const* d_in, const int* in_sizes, int n_in,
                              void* d_out, int out_size, void* d_ws, size_t ws_size,
                              hipStream_t stream)
{
    const float* X      = (const float*)d_in[0];  // [128,256,128]
    const float* hidden = (const float*)d_in[1];  // [128,1024]
    const float* W_in   = (const float*)d_in[2];  // [1024,128]
    const float* W_hh   = (const float*)d_in[3];  // [1024,1024]
    const float* b_hh   = (const float*)d_in[4];  // [1024]
    const float* W_out  = (const float*)d_in[5];  // [128,1024]
    const float* alpha  = (const float*)d_in[6];  // [1024]
    const float* noise  = (const float*)d_in[7];  // [256,1024]

    char* ws = (char*)d_ws;   // needs ~10.2 MB
    unsigned short* Xh = (unsigned short*)(ws + OFF_XH);
    float*          NB = (float*)(ws + OFF_NB);
    unsigned short* Wo = (unsigned short*)(ws + OFF_WO);
    unsigned int*  Hb0 = (unsigned int*)(ws + OFF_HB);
    unsigned int*  Hb1 = Hb0 + (size_t)B_ * NH / 2;
    unsigned int*  cnt = (unsigned int*)(ws + OFF_CNT);

    float* hidden_list = (float*)d_out;                                  // [128,256,1024]
    float* output_list = hidden_list + (size_t)B_ * T_ * NH;             // [128,256,128]
    float* h_final     = output_list + (size_t)B_ * T_ * NIN;            // [128,1024]

    setup_kernel<<<(B_ * T_ * NIN + 255) / 256, 256, 0, stream>>>(
        X, hidden, b_hh, W_out, alpha, noise, Xh, NB, Wo, Hb0, cnt);

    rnn_step_kernel<<<GM * GN, 256, 0, stream>>>(
        W_hh, W_in, Xh, NB, Hb0, Hb1, cnt, hidden_list, h_final);

    ygemm_kernel<<<(B_ * T_) / 64, 256, 0, stream>>>(
        hidden_list, Wo, output_list);
}